// Round 12
// baseline (366.570 us; speedup 1.0000x reference)
//
#include <hip/hip_runtime.h>
#include <hip/hip_fp16.h>
#include <math.h>

// Workspace (halves unless noted): z (Nn*256) + xh/hh (Nn*256, aliased) + W1t/W2t
// (256*256 each) + esrc (E int) + CSR ints + el/er floats  ≈ 56 MB.
// erank (E int) lives in d_out (51 MB, dead until the final aggregate writes it).

typedef _Float16 half8 __attribute__((ext_vector_type(8)));
typedef float floatx4 __attribute__((ext_vector_type(4)));

__device__ __forceinline__ float rl_f(float x, int i) {
  return __int_as_float(__builtin_amdgcn_readlane(__float_as_int(x), i));
}
__device__ __forceinline__ unsigned pk2(float a, float b) {  // 2x fp32 -> packed fp16
  return (unsigned)__half_as_ushort(__float2half_rn(a)) |
         ((unsigned)__half_as_ushort(__float2half_rn(b)) << 16);
}

// 4x fp16 (uint2) * scalar e accumulated into float4 — fmaf(fpext(h), e, acc)
// pattern-matches to v_fma_mix_f32. e is wave-uniform (SGPR) in the hot loop.
__device__ __forceinline__ void fma_row(float4& acc, uint2 zv, float e) {
  union { uint2 u; __half h[4]; } w;
  w.u = zv;
  acc.x = fmaf(__half2float(w.h[0]), e, acc.x);
  acc.y = fmaf(__half2float(w.h[1]), e, acc.y);
  acc.z = fmaf(__half2float(w.h[2]), e, acc.z);
  acc.w = fmaf(__half2float(w.h[3]), e, acc.w);
}

// ---------- fused prep: W transpose + zero region + x fp32->fp16 ----------
__global__ __launch_bounds__(256) void prep(const float* __restrict__ W1,
                                            const float* __restrict__ W2,
                                            unsigned short* __restrict__ w1t,
                                            unsigned short* __restrict__ w2t,
                                            const float4* __restrict__ x,
                                            uint2* __restrict__ xh, int n4cvt,
                                            float4* __restrict__ zp, int zn4, int NZ) {
  const int b = blockIdx.x, t = threadIdx.x;
  if (b < 512) {
    const float* W = (b < 256) ? W1 : W2;
    unsigned short* Wt = (b < 256) ? w1t : w2t;
    const int k = b & 255;
    Wt[t * 256 + k] = __half_as_ushort(__float2half_rn(W[k * 256 + t]));
  } else if (b < 512 + NZ) {
    const int i = (b - 512) * 256 + t;
    if (i < zn4) zp[i] = make_float4(0.f, 0.f, 0.f, 0.f);
  } else {
    const int i = (b - 512 - NZ) * 256 + t;
    if (i < n4cvt) {
      float4 v = x[i];
      uint2 o;
      o.x = pk2(v.x, v.y);
      o.y = pk2(v.z, v.w);
      xh[i] = o;
    }
  }
}

// ---------- CSR build: ONE returning-atomic pass ----------
__global__ __launch_bounds__(256) void hist_rank(const int* __restrict__ dst,
                                                 int* __restrict__ counts,
                                                 int* __restrict__ erank, int E) {
  int i = blockIdx.x * 256 + threadIdx.x;
  if (i < E) erank[i] = atomicAdd(&counts[dst[i]], 1);
}

__global__ __launch_bounds__(256) void scan_block(const int* __restrict__ counts,
                                                  int* __restrict__ offsets,
                                                  int* __restrict__ bsum, int Nn) {
  __shared__ int sm[256];
  int t = threadIdx.x;
  int i = blockIdx.x * 256 + t;
  int v = (i < Nn) ? counts[i] : 0;
  sm[t] = v;
  __syncthreads();
  for (int off = 1; off < 256; off <<= 1) {
    int x = (t >= off) ? sm[t - off] : 0;
    __syncthreads();
    sm[t] += x;
    __syncthreads();
  }
  if (i < Nn) offsets[i] = sm[t] - v;
  if (t == 255) bsum[blockIdx.x] = sm[255];
}

// scan_add2: each block b computes its own exclusive bsum-prefix via a 256-wide
// LDS scan (NB<=256), then adds it to the per-block offsets.
__global__ __launch_bounds__(256) void scan_add2(int* __restrict__ offsets,
                                                 const int* __restrict__ bsum,
                                                 int Nn, int NB) {
  __shared__ int sm[256];
  const int t = threadIdx.x, b = blockIdx.x;
  int v = (t < NB && t < b) ? bsum[t] : 0;
  sm[t] = v;
  __syncthreads();
  for (int off = 1; off < 256; off <<= 1) {
    int x = (t >= off) ? sm[t - off] : 0;
    __syncthreads();
    sm[t] += x;
    __syncthreads();
  }
  const int bofs = sm[255];  // sum of bsum[0..b)
  const int i = b * 256 + t;
  if (i < Nn) offsets[i] += bofs;
}

// ---------- MFMA GEMM v6: persistent-B + A prefetch + ATOMIC-FREE attn dots ----
// C[M,256] = A[M,256] @ Wt^T, A fp16. Block = 4 waves; wave wv owns cols
// [64wv,64wv+64); B slice loaded once into 128 VGPRs. Grid-strides over 16-row
// chunks (A fragments double-buffered across chunks: loads for c+1 issue before
// compute of c). Each chunk's 16 rows are owned by exactly ONE block, so the
// el/er attention dots combine across the 4 waves via a 1KB double-buffered LDS
// buffer + plain coalesced stores — the previous atomicAdd epilogue issued 400k
// device atomics per gemm (~ the cost of hist_rank's 800k, R10/R11 counters).
// SCAT (gemm1 only): after the gemm loop each block places its 1/grid slice of
// edges into esrc (latency-bound; overlaps other blocks' gemm compute).
// Lane (ln,kg) holds C[m0+ln][wv*64 + t*16 + kg*4 + 0..3] in acc[t].

__device__ __forceinline__ void gemm_load_a(half8* af, const unsigned short* __restrict__ A,
                                            int row, int kg) {
  const unsigned short* ap = A + (size_t)row * 256 + kg * 8;
#pragma unroll
  for (int kb = 0; kb < 8; kb++) af[kb] = *(const half8*)(ap + kb * 32);
}

// lred layout: [par][sel(el/er)][wave][row16] floats
template <int HS>
__device__ __forceinline__ void gemm_compute_store(const half8 (&bf)[8][4], const half8* af,
                                                   int m0, int tid, int lane, int ln, int kg,
                                                   int wv, int par,
                                                   const float* __restrict__ al,
                                                   const float* __restrict__ ar,
                                                   float* __restrict__ el,
                                                   float* __restrict__ er,
                                                   unsigned short* __restrict__ C, int M,
                                                   float* __restrict__ lred) {
  floatx4 acc[4];
#pragma unroll
  for (int t = 0; t < 4; t++) acc[t] = (floatx4)0.f;
#pragma unroll
  for (int kb = 0; kb < 8; kb++)
#pragma unroll
    for (int t = 0; t < 4; t++)
      acc[t] = __builtin_amdgcn_mfma_f32_16x16x32_f16(bf[kb][t], af[kb], acc[t], 0, 0, 0);

  // attn dot partials over this wave's 64 cols
  const int cb = wv * 64 + kg * 4;
  float pl = 0.f, pr = 0.f;
#pragma unroll
  for (int t = 0; t < 4; t++) {
    float4 av = *(const float4*)(al + cb + t * 16);
    float4 rv = *(const float4*)(ar + cb + t * 16);
    pl += acc[t].x * av.x + acc[t].y * av.y + acc[t].z * av.z + acc[t].w * av.w;
    pr += acc[t].x * rv.x + acc[t].y * rv.y + acc[t].z * rv.z + acc[t].w * rv.w;
  }
  pl += __shfl_xor(pl, 16); pl += __shfl_xor(pl, 32);  // sum over kg; all lanes hold row (lane&15)
  pr += __shfl_xor(pr, 16); pr += __shfl_xor(pr, 32);

  if (lane < 16) {
    lred[((par * 2 + 0) * 4 + wv) * 16 + lane] = pl;
    lred[((par * 2 + 1) * 4 + wv) * 16 + lane] = pr;
  }
  __syncthreads();

  // cross-wave combine + plain store (block exclusively owns these rows)
  if (HS) {
    if (tid < 64) {
      const int sel = tid >> 5, rh = tid & 31, r = rh >> 1, h = rh & 1;
      if (m0 + r < M) {
        float v = lred[((par * 2 + sel) * 4 + 2 * h) * 16 + r] +
                  lred[((par * 2 + sel) * 4 + 2 * h + 1) * 16 + r];
        (sel ? er : el)[(m0 + r) * 2 + h] = v;
      }
    }
  } else {
    if (tid < 32) {
      const int sel = tid >> 4, r = tid & 15;
      if (m0 + r < M) {
        float v = lred[((par * 2 + sel) * 4 + 0) * 16 + r] +
                  lred[((par * 2 + sel) * 4 + 1) * 16 + r] +
                  lred[((par * 2 + sel) * 4 + 2) * 16 + r] +
                  lred[((par * 2 + sel) * 4 + 3) * 16 + r];
        (sel ? er : el)[m0 + r] = v;
      }
    }
  }

  const int row = m0 + ln;
  if (row < M) {
    unsigned short* cp = C + (size_t)row * 256 + wv * 64 + kg * 4;
#pragma unroll
    for (int t = 0; t < 4; t++) {
      uint2 o;
      o.x = pk2(acc[t].x, acc[t].y);
      o.y = pk2(acc[t].z, acc[t].w);
      *(uint2*)(cp + t * 16) = o;
    }
  }
}

template <int HS, int SCAT>
__global__ __launch_bounds__(256, 2) void gemm_mfma(const unsigned short* __restrict__ A,
                                                    const unsigned short* __restrict__ Wt,
                                                    unsigned short* __restrict__ C,
                                                    const float* __restrict__ al,
                                                    const float* __restrict__ ar,
                                                    float* __restrict__ el,
                                                    float* __restrict__ er, int M,
                                                    const int* __restrict__ src,
                                                    const int* __restrict__ dst,
                                                    const int* __restrict__ offs,
                                                    const int* __restrict__ erank,
                                                    int* __restrict__ esrc, int E) {
  __shared__ float lred[2 * 2 * 4 * 16];  // [par][el/er][wave][row16]
  const int tid = threadIdx.x;
  const int wv = tid >> 6, lane = tid & 63;
  const int ln = lane & 15, kg = lane >> 4;

  // persistent B: wave wv owns col-tiles T = 4*wv + t, t = 0..3
  half8 bf[8][4];
#pragma unroll
  for (int kb = 0; kb < 8; kb++)
#pragma unroll
    for (int t = 0; t < 4; t++)
      bf[kb][t] = *(const half8*)(Wt + (size_t)((4 * wv + t) * 16 + ln) * 256 +
                                  kb * 32 + kg * 8);

  const int nchunk = (M + 15) >> 4;
  const int stride = gridDim.x;
  int c0 = blockIdx.x;

  if (c0 < nchunk) {
    half8 af0[8], af1[8];
    gemm_load_a(af0, A, min(c0 * 16 + ln, M - 1), kg);
    int c1 = c0 + stride;

    for (;;) {
      if (c1 < nchunk) gemm_load_a(af1, A, min(c1 * 16 + ln, M - 1), kg);
      gemm_compute_store<HS>(bf, af0, c0 << 4, tid, lane, ln, kg, wv, 0,
                             al, ar, el, er, C, M, lred);
      if (c1 >= nchunk) break;
      const int c2 = c1 + stride;
      if (c2 < nchunk) gemm_load_a(af0, A, min(c2 * 16 + ln, M - 1), kg);
      gemm_compute_store<HS>(bf, af1, c1 << 4, tid, lane, ln, kg, wv, 1,
                             al, ar, el, er, C, M, lred);
      if (c2 >= nchunk) break;
      c0 = c2;
      c1 = c2 + stride;
    }
  }

  // scatter tail (gemm1): place this block's slice of edges. Runs as each block
  // retires from gemm -> overlaps other blocks' compute.
  if (SCAT) {
    const int per = (E + (int)gridDim.x - 1) / (int)gridDim.x;
    const int b0 = blockIdx.x * per;
    const int b1 = min(E, b0 + per);
    for (int i = b0 + tid; i < b1; i += 256)
      esrc[offs[dst[i]] + erank[i]] = src[i];
  }
}

// ---------- fused per-node GAT aggregation, no-max softmax (R3/R7 shape) ----------
// One wave per dst node; z gathered as uint2/lane (full 512B row per pass).
// KEY: per-edge src index and weight go through v_readlane into SGPRs -> the
// gather compiles to scalar-base global_load and the FMA takes the weight as
// an SGPR operand. (uint4/shfl variants regressed 20%: R4/R6.) At roofline:
// delivered gather BW ~6.8 TB/s (L2-assisted); HBM FETCH = compulsory.
template <int HS, int RELU, int OUTH>
__global__ __launch_bounds__(256) void node_aggregate(const unsigned short* __restrict__ z,
                                                      const float* __restrict__ el,
                                                      const float* __restrict__ er,
                                                      const int* __restrict__ esrc,
                                                      const int* __restrict__ offsets,
                                                      const int* __restrict__ counts,
                                                      const float* __restrict__ bias,
                                                      void* __restrict__ out,
                                                      int n0, int cnt_nodes) {
  int wid = (blockIdx.x * 256 + threadIdx.x) >> 6;
  int lane = threadIdx.x & 63;
  if (wid >= cnt_nodes) return;
  const int n = n0 + wid;
  const int beg = offsets[n];
  const int deg = counts[n];
  float ern0, ern1 = 0.f;
  if (HS) {
    float2 e = ((const float2*)er)[n];
    ern0 = e.x; ern1 = e.y;
  } else {
    ern0 = er[n];
  }
  const int head = HS ? (lane >> 5) : 0;  // lane owns cols [4*lane,4*lane+4)

  float s0 = 0.f, s1 = 0.f;
  float4 acc = make_float4(0.f, 0.f, 0.f, 0.f);
  const uint2* zp = (const uint2*)z;

  for (int base = 0; base < deg; base += 64) {
    const int cnt = min(64, deg - base);
    int sn = 0;
    float myex0 = 0.f, myex1 = 0.f;
    if (lane < cnt) {
      sn = esrc[beg + base + lane];
      if (HS) {
        float2 elv = ((const float2*)el)[sn];
        float v0 = elv.x + ern0; v0 = (v0 > 0.f) ? v0 : 0.2f * v0;
        float v1 = elv.y + ern1; v1 = (v1 > 0.f) ? v1 : 0.2f * v1;
        myex0 = __expf(v0);
        myex1 = __expf(v1);
      } else {
        float v0 = el[sn] + ern0; v0 = (v0 > 0.f) ? v0 : 0.2f * v0;
        myex0 = __expf(v0);
      }
      s0 += myex0;
      s1 += myex1;
    }

    int i = 0;
    for (; i + 8 <= cnt; i += 8) {
      int s_[8];
      float e_[8];
      uint2 zv[8];
#pragma unroll
      for (int j = 0; j < 8; j++) {
        s_[j] = __builtin_amdgcn_readlane(sn, i + j);
        float e0 = rl_f(myex0, i + j);
        if (HS) {
          float e1 = rl_f(myex1, i + j);
          e_[j] = head ? e1 : e0;
        } else {
          e_[j] = e0;
        }
      }
#pragma unroll
      for (int j = 0; j < 8; j++) zv[j] = zp[((size_t)s_[j] << 6) + lane];
#pragma unroll
      for (int j = 0; j < 8; j++) fma_row(acc, zv[j], e_[j]);
    }
    for (; i < cnt; i++) {
      int si = __builtin_amdgcn_readlane(sn, i);
      float e = rl_f(myex0, i);
      if (HS) {
        float e1 = rl_f(myex1, i);
        if (head) e = e1;
      }
      uint2 zv = zp[((size_t)si << 6) + lane];
      fma_row(acc, zv, e);
    }
  }

#pragma unroll
  for (int o = 32; o > 0; o >>= 1) {
    s0 += __shfl_xor(s0, o);
    if (HS) s1 += __shfl_xor(s1, o);
  }
  const float s = (HS && head) ? s1 : s0;
  float4 bb = ((const float4*)bias)[lane];
  float4 v;
  if (deg > 0) {
    float inv = 1.f / s;
    v = make_float4(acc.x * inv + bb.x, acc.y * inv + bb.y,
                    acc.z * inv + bb.z, acc.w * inv + bb.w);
  } else {
    v = bb;
  }
  if (RELU) {
    v.x = fmaxf(v.x, 0.f); v.y = fmaxf(v.y, 0.f);
    v.z = fmaxf(v.z, 0.f); v.w = fmaxf(v.w, 0.f);
  }
  if (OUTH) {
    uint2 o;
    o.x = pk2(v.x, v.y);
    o.y = pk2(v.z, v.w);
    ((uint2*)out)[((size_t)n << 6) + lane] = o;
  } else {
    ((float4*)out)[((size_t)n << 6) + lane] = v;
  }
}

extern "C" void kernel_launch(void* const* d_in, const int* in_sizes, int n_in,
                              void* d_out, int out_size, void* d_ws, size_t ws_size,
                              hipStream_t stream) {
  const float* x   = (const float*)d_in[0];
  const int*   src = (const int*)d_in[1];
  const int*   dst = (const int*)d_in[2];
  const float* W1  = (const float*)d_in[3];
  const float* al1 = (const float*)d_in[4];
  const float* ar1 = (const float*)d_in[5];
  const float* b1  = (const float*)d_in[6];
  const float* W2  = (const float*)d_in[7];
  const float* al2 = (const float*)d_in[8];
  const float* ar2 = (const float*)d_in[9];
  const float* b2  = (const float*)d_in[10];
  float* out = (float*)d_out;
  (void)n_in; (void)out_size; (void)ws_size;

  const int Nn = in_sizes[0] / 256;  // 50000
  const int Ee = in_sizes[1];        // 800000
  const int F = 256;
  const int NB = (Nn + 255) / 256;

  // workspace layout
  unsigned short* z   = (unsigned short*)d_ws;      // Nn*256 fp16
  unsigned short* xh  = z + (size_t)Nn * F;         // Nn*256 fp16 (x cvt; then h)
  unsigned short* w1t = xh + (size_t)Nn * F;        // 256*256 fp16
  unsigned short* w2t = w1t + 65536;                // 256*256 fp16
  int*   esrc   = (int*)(w2t + 65536);              // Ee
  int*   counts = esrc + Ee;                        // Nn
  int*   offs   = counts + Nn;                      // Nn
  int*   cursor = offs + Nn;                        // Nn (unused; layout kept)
  int*   bsum   = cursor + Nn;                      // 256
  int*   bofs   = bsum + 256;                       // 256 (unused; layout kept)
  float* el1p   = (float*)(bofs + 256);             // Nn*2
  float* er1p   = el1p + (size_t)Nn * 2;            // Nn*2
  float* el2p   = er1p + (size_t)Nn * 2;            // Nn
  float* er2p   = el2p + Nn;                        // Nn
  int*   erank  = (int*)d_out;                      // Ee; d_out dead until final agg

  dim3 blk(256);

  // ---- fused prep: transpose W1/W2 + zero counts..er2p + cvt x->fp16 ----
  const int zn4 = (9 * Nn + 512) / 4;       // ints / 4
  const int NZ = (zn4 + 255) / 256;
  const int n4cvt = Nn * 64;                // float4 count of x
  const int NC = (n4cvt + 255) / 256;
  prep<<<512 + NZ + NC, blk, 0, stream>>>(W1, W2, w1t, w2t, (const float4*)x,
                                          (uint2*)xh, n4cvt, (float4*)counts, zn4, NZ);

  // ---- CSR build: one returning-atomic pass + scan (placement fused in gemm1) ----
  const int EB = (Ee + 255) / 256;
  hist_rank<<<EB, blk, 0, stream>>>(dst, counts, erank, Ee);
  scan_block<<<NB, blk, 0, stream>>>(counts, offs, bsum, Nn);
  scan_add2<<<NB, blk, 0, stream>>>(offs, bsum, Nn, NB);

  const int gemm_grid = 512;  // 2 blocks/CU

  // ---- layer 1 (heads=2, d=128); gemm1 also places esrc in its tail ----
  gemm_mfma<1, 1><<<gemm_grid, blk, 0, stream>>>(xh, w1t, z, al1, ar1, el1p, er1p, Nn,
                                                 src, dst, offs, erank, esrc, Ee);
  node_aggregate<1, 1, 1><<<(Nn + 3) / 4, blk, 0, stream>>>(z, el1p, er1p, esrc, offs,
                                                            counts, b1, xh, 0, Nn);

  // ---- layer 2 (heads=1, d=256) ----
  gemm_mfma<0, 0><<<gemm_grid, blk, 0, stream>>>(xh, w2t, z, al2, ar2, el2p, er2p, Nn,
                                                 nullptr, nullptr, nullptr, nullptr,
                                                 nullptr, 0);
  node_aggregate<0, 0, 0><<<(Nn + 3) / 4, blk, 0, stream>>>(z, el2p, er2p, esrc, offs,
                                                            counts, b2, out, 0, Nn);
}

// Round 13
// 344.688 us; speedup vs baseline: 1.0635x; 1.0635x over previous
//
#include <hip/hip_runtime.h>
#include <hip/hip_fp16.h>
#include <math.h>

// Workspace (halves unless noted): z (Nn*256) + xh/hh (Nn*256, aliased) + W1t/W2t
// (256*256 each) + esrc (E int) + CSR ints + el/er floats  ≈ 56 MB.
// erank (E int) aliases z: only live between hist_rank and scatter_pos, both of
// which complete (stream-ordered) before gemm1 writes z.

typedef _Float16 half8 __attribute__((ext_vector_type(8)));
typedef float floatx4 __attribute__((ext_vector_type(4)));

__device__ __forceinline__ float rl_f(float x, int i) {
  return __int_as_float(__builtin_amdgcn_readlane(__float_as_int(x), i));
}
__device__ __forceinline__ unsigned pk2(float a, float b) {  // 2x fp32 -> packed fp16
  return (unsigned)__half_as_ushort(__float2half_rn(a)) |
         ((unsigned)__half_as_ushort(__float2half_rn(b)) << 16);
}

// 4x fp16 (uint2) * scalar e accumulated into float4 — fmaf(fpext(h), e, acc)
// pattern-matches to v_fma_mix_f32. e is wave-uniform (SGPR) in the hot loop.
__device__ __forceinline__ void fma_row(float4& acc, uint2 zv, float e) {
  union { uint2 u; __half h[4]; } w;
  w.u = zv;
  acc.x = fmaf(__half2float(w.h[0]), e, acc.x);
  acc.y = fmaf(__half2float(w.h[1]), e, acc.y);
  acc.z = fmaf(__half2float(w.h[2]), e, acc.z);
  acc.w = fmaf(__half2float(w.h[3]), e, acc.w);
}

// ---------- fused prep: W transpose + zero region + x fp32->fp16 ----------
__global__ __launch_bounds__(256) void prep(const float* __restrict__ W1,
                                            const float* __restrict__ W2,
                                            unsigned short* __restrict__ w1t,
                                            unsigned short* __restrict__ w2t,
                                            const float4* __restrict__ x,
                                            uint2* __restrict__ xh, int n4cvt,
                                            float4* __restrict__ zp, int zn4, int NZ) {
  const int b = blockIdx.x, t = threadIdx.x;
  if (b < 512) {
    const float* W = (b < 256) ? W1 : W2;
    unsigned short* Wt = (b < 256) ? w1t : w2t;
    const int k = b & 255;
    Wt[t * 256 + k] = __half_as_ushort(__float2half_rn(W[k * 256 + t]));
  } else if (b < 512 + NZ) {
    const int i = (b - 512) * 256 + t;
    if (i < zn4) zp[i] = make_float4(0.f, 0.f, 0.f, 0.f);
  } else {
    const int i = (b - 512 - NZ) * 256 + t;
    if (i < n4cvt) {
      float4 v = x[i];
      uint2 o;
      o.x = pk2(v.x, v.y);
      o.y = pk2(v.z, v.w);
      xh[i] = o;
    }
  }
}

// ---------- CSR build: ONE returning-atomic pass ----------
// erank[i] = this edge's arrival rank among edges with the same dst. Histogram
// and rank in one pass -> halves the 64B-line returning-atomic traffic vs the
// old hist+cursor-scatter pair (R10: 2x ~50us, WRITE 52MB per pass).
__global__ __launch_bounds__(256) void hist_rank(const int* __restrict__ dst,
                                                 int* __restrict__ counts,
                                                 int* __restrict__ erank, int E) {
  int i = blockIdx.x * 256 + threadIdx.x;
  if (i < E) erank[i] = atomicAdd(&counts[dst[i]], 1);
}

// placement pass: no atomics. offs is 200KB (L2-resident), esrc store random 4B.
__global__ __launch_bounds__(256) void scatter_pos(const int* __restrict__ src,
                                                   const int* __restrict__ dst,
                                                   const int* __restrict__ offs,
                                                   const int* __restrict__ erank,
                                                   int* __restrict__ esrc, int E) {
  int i = blockIdx.x * 256 + threadIdx.x;
  if (i < E) esrc[offs[dst[i]] + erank[i]] = src[i];
}

__global__ __launch_bounds__(256) void scan_block(const int* __restrict__ counts,
                                                  int* __restrict__ offsets,
                                                  int* __restrict__ bsum, int Nn) {
  __shared__ int sm[256];
  int t = threadIdx.x;
  int i = blockIdx.x * 256 + t;
  int v = (i < Nn) ? counts[i] : 0;
  sm[t] = v;
  __syncthreads();
  for (int off = 1; off < 256; off <<= 1) {
    int x = (t >= off) ? sm[t - off] : 0;
    __syncthreads();
    sm[t] += x;
    __syncthreads();
  }
  if (i < Nn) offsets[i] = sm[t] - v;
  if (t == 255) bsum[blockIdx.x] = sm[255];
}

// scan_add2: each block b computes its own exclusive bsum-prefix via a 256-wide
// LDS scan (NB<=256), then adds it to the per-block offsets.
__global__ __launch_bounds__(256) void scan_add2(int* __restrict__ offsets,
                                                 const int* __restrict__ bsum,
                                                 int Nn, int NB) {
  __shared__ int sm[256];
  const int t = threadIdx.x, b = blockIdx.x;
  int v = (t < NB && t < b) ? bsum[t] : 0;
  sm[t] = v;
  __syncthreads();
  for (int off = 1; off < 256; off <<= 1) {
    int x = (t >= off) ? sm[t - off] : 0;
    __syncthreads();
    sm[t] += x;
    __syncthreads();
  }
  const int bofs = sm[255];  // sum of bsum[0..b)
  const int i = b * 256 + t;
  if (i < Nn) offsets[i] += bofs;
}

// ---------- MFMA GEMM v5: persistent-B + fused attn dots + A prefetch ----------
// C[M,256] = A[M,256] @ Wt^T, A fp16. Block = 4 waves; wave wv owns cols
// [64wv,64wv+64) (4 N-tiles), B slice loaded once into 128 VGPRs. Grid-strides
// over 16-row chunks with a software pipeline (chunk c+1's A-loads issue before
// chunk c's compute). Epilogue: el/er dots + NON-RETURNING atomicAdd — these
// are fire-and-forget (pipelined, ~free); the R12 LDS-barrier variant that
// replaced them was SLOWER (4-wave lockstep per chunk). el/er pre-zeroed.
// Lane (ln,kg) holds C[m0+ln][wv*64 + t*16 + kg*4 + 0..3] in acc[t].

__device__ __forceinline__ void gemm_load_a(half8* af, const unsigned short* __restrict__ A,
                                            int row, int kg) {
  const unsigned short* ap = A + (size_t)row * 256 + kg * 8;
#pragma unroll
  for (int kb = 0; kb < 8; kb++) af[kb] = *(const half8*)(ap + kb * 32);
}

template <int HS>
__device__ __forceinline__ void gemm_compute_store(const half8 (&bf)[8][4], const half8* af,
                                                   int m0, int lane, int ln, int kg, int wv,
                                                   const float* __restrict__ al,
                                                   const float* __restrict__ ar,
                                                   float* __restrict__ el,
                                                   float* __restrict__ er,
                                                   unsigned short* __restrict__ C, int M) {
  floatx4 acc[4];
#pragma unroll
  for (int t = 0; t < 4; t++) acc[t] = (floatx4)0.f;
#pragma unroll
  for (int kb = 0; kb < 8; kb++)
#pragma unroll
    for (int t = 0; t < 4; t++)
      acc[t] = __builtin_amdgcn_mfma_f32_16x16x32_f16(bf[kb][t], af[kb], acc[t], 0, 0, 0);

  // fused attn dots over this wave's 64 cols (av/rv are L1-resident; loading
  // them here instead of preloading keeps VGPR under the 2-waves/SIMD cap)
  const int cb = wv * 64 + kg * 4;
  float pl = 0.f, pr = 0.f;
#pragma unroll
  for (int t = 0; t < 4; t++) {
    float4 av = *(const float4*)(al + cb + t * 16);
    float4 rv = *(const float4*)(ar + cb + t * 16);
    pl += acc[t].x * av.x + acc[t].y * av.y + acc[t].z * av.z + acc[t].w * av.w;
    pr += acc[t].x * rv.x + acc[t].y * rv.y + acc[t].z * rv.z + acc[t].w * rv.w;
  }
  pl += __shfl_xor(pl, 16); pl += __shfl_xor(pl, 32);
  pr += __shfl_xor(pr, 16); pr += __shfl_xor(pr, 32);

  const int row = m0 + ln;
  if (row < M) {
    if (lane < 16) {  // kg == 0
      const int idx = HS ? (row * 2 + (wv >> 1)) : row;
      atomicAdd(&el[idx], pl);
      atomicAdd(&er[idx], pr);
    }
    unsigned short* cp = C + (size_t)row * 256 + wv * 64 + kg * 4;
#pragma unroll
    for (int t = 0; t < 4; t++) {
      uint2 o;
      o.x = pk2(acc[t].x, acc[t].y);
      o.y = pk2(acc[t].z, acc[t].w);
      *(uint2*)(cp + t * 16) = o;
    }
  }
}

template <int HS>
__global__ __launch_bounds__(256, 2) void gemm_mfma(const unsigned short* __restrict__ A,
                                                    const unsigned short* __restrict__ Wt,
                                                    unsigned short* __restrict__ C,
                                                    const float* __restrict__ al,
                                                    const float* __restrict__ ar,
                                                    float* __restrict__ el,
                                                    float* __restrict__ er, int M) {
  const int tid = threadIdx.x;
  const int wv = tid >> 6, lane = tid & 63;
  const int ln = lane & 15, kg = lane >> 4;

  // persistent B: wave wv owns col-tiles T = 4*wv + t, t = 0..3
  half8 bf[8][4];
#pragma unroll
  for (int kb = 0; kb < 8; kb++)
#pragma unroll
    for (int t = 0; t < 4; t++)
      bf[kb][t] = *(const half8*)(Wt + (size_t)((4 * wv + t) * 16 + ln) * 256 +
                                  kb * 32 + kg * 8);

  const int nchunk = (M + 15) >> 4;
  const int stride = gridDim.x;
  int c0 = blockIdx.x;
  if (c0 >= nchunk) return;

  half8 af0[8], af1[8];
  gemm_load_a(af0, A, min(c0 * 16 + ln, M - 1), kg);
  int c1 = c0 + stride;

  for (;;) {
    if (c1 < nchunk) gemm_load_a(af1, A, min(c1 * 16 + ln, M - 1), kg);
    gemm_compute_store<HS>(bf, af0, c0 << 4, lane, ln, kg, wv, al, ar, el, er, C, M);
    if (c1 >= nchunk) break;
    const int c2 = c1 + stride;
    if (c2 < nchunk) gemm_load_a(af0, A, min(c2 * 16 + ln, M - 1), kg);
    gemm_compute_store<HS>(bf, af1, c1 << 4, lane, ln, kg, wv, al, ar, el, er, C, M);
    if (c2 >= nchunk) break;
    c0 = c2;
    c1 = c2 + stride;
  }
}

// ---------- fused per-node GAT aggregation, no-max softmax (R3/R7 shape) ----------
// One wave per dst node; z gathered as uint2/lane (full 512B row per pass).
// KEY: per-edge src index and weight go through v_readlane into SGPRs -> the
// gather compiles to scalar-base global_load and the FMA takes the weight as
// an SGPR operand. (uint4/shfl variants regressed 20%: R4/R6.) At roofline:
// delivered gather BW ~6.8 TB/s (L2-assisted); HBM FETCH = compulsory.
template <int HS, int RELU, int OUTH>
__global__ __launch_bounds__(256) void node_aggregate(const unsigned short* __restrict__ z,
                                                      const float* __restrict__ el,
                                                      const float* __restrict__ er,
                                                      const int* __restrict__ esrc,
                                                      const int* __restrict__ offsets,
                                                      const int* __restrict__ counts,
                                                      const float* __restrict__ bias,
                                                      void* __restrict__ out,
                                                      int n0, int cnt_nodes) {
  int wid = (blockIdx.x * 256 + threadIdx.x) >> 6;
  int lane = threadIdx.x & 63;
  if (wid >= cnt_nodes) return;
  const int n = n0 + wid;
  const int beg = offsets[n];
  const int deg = counts[n];
  float ern0, ern1 = 0.f;
  if (HS) {
    float2 e = ((const float2*)er)[n];
    ern0 = e.x; ern1 = e.y;
  } else {
    ern0 = er[n];
  }
  const int head = HS ? (lane >> 5) : 0;  // lane owns cols [4*lane,4*lane+4)

  float s0 = 0.f, s1 = 0.f;
  float4 acc = make_float4(0.f, 0.f, 0.f, 0.f);
  const uint2* zp = (const uint2*)z;

  for (int base = 0; base < deg; base += 64) {
    const int cnt = min(64, deg - base);
    int sn = 0;
    float myex0 = 0.f, myex1 = 0.f;
    if (lane < cnt) {
      sn = esrc[beg + base + lane];
      if (HS) {
        float2 elv = ((const float2*)el)[sn];
        float v0 = elv.x + ern0; v0 = (v0 > 0.f) ? v0 : 0.2f * v0;
        float v1 = elv.y + ern1; v1 = (v1 > 0.f) ? v1 : 0.2f * v1;
        myex0 = __expf(v0);
        myex1 = __expf(v1);
      } else {
        float v0 = el[sn] + ern0; v0 = (v0 > 0.f) ? v0 : 0.2f * v0;
        myex0 = __expf(v0);
      }
      s0 += myex0;
      s1 += myex1;
    }

    int i = 0;
    for (; i + 8 <= cnt; i += 8) {
      int s_[8];
      float e_[8];
      uint2 zv[8];
#pragma unroll
      for (int j = 0; j < 8; j++) {
        s_[j] = __builtin_amdgcn_readlane(sn, i + j);
        float e0 = rl_f(myex0, i + j);
        if (HS) {
          float e1 = rl_f(myex1, i + j);
          e_[j] = head ? e1 : e0;
        } else {
          e_[j] = e0;
        }
      }
#pragma unroll
      for (int j = 0; j < 8; j++) zv[j] = zp[((size_t)s_[j] << 6) + lane];
#pragma unroll
      for (int j = 0; j < 8; j++) fma_row(acc, zv[j], e_[j]);
    }
    for (; i < cnt; i++) {
      int si = __builtin_amdgcn_readlane(sn, i);
      float e = rl_f(myex0, i);
      if (HS) {
        float e1 = rl_f(myex1, i);
        if (head) e = e1;
      }
      uint2 zv = zp[((size_t)si << 6) + lane];
      fma_row(acc, zv, e);
    }
  }

#pragma unroll
  for (int o = 32; o > 0; o >>= 1) {
    s0 += __shfl_xor(s0, o);
    if (HS) s1 += __shfl_xor(s1, o);
  }
  const float s = (HS && head) ? s1 : s0;
  float4 bb = ((const float4*)bias)[lane];
  float4 v;
  if (deg > 0) {
    float inv = 1.f / s;
    v = make_float4(acc.x * inv + bb.x, acc.y * inv + bb.y,
                    acc.z * inv + bb.z, acc.w * inv + bb.w);
  } else {
    v = bb;
  }
  if (RELU) {
    v.x = fmaxf(v.x, 0.f); v.y = fmaxf(v.y, 0.f);
    v.z = fmaxf(v.z, 0.f); v.w = fmaxf(v.w, 0.f);
  }
  if (OUTH) {
    uint2 o;
    o.x = pk2(v.x, v.y);
    o.y = pk2(v.z, v.w);
    ((uint2*)out)[((size_t)n << 6) + lane] = o;
  } else {
    ((float4*)out)[((size_t)n << 6) + lane] = v;
  }
}

extern "C" void kernel_launch(void* const* d_in, const int* in_sizes, int n_in,
                              void* d_out, int out_size, void* d_ws, size_t ws_size,
                              hipStream_t stream) {
  const float* x   = (const float*)d_in[0];
  const int*   src = (const int*)d_in[1];
  const int*   dst = (const int*)d_in[2];
  const float* W1  = (const float*)d_in[3];
  const float* al1 = (const float*)d_in[4];
  const float* ar1 = (const float*)d_in[5];
  const float* b1  = (const float*)d_in[6];
  const float* W2  = (const float*)d_in[7];
  const float* al2 = (const float*)d_in[8];
  const float* ar2 = (const float*)d_in[9];
  const float* b2  = (const float*)d_in[10];
  float* out = (float*)d_out;
  (void)n_in; (void)out_size; (void)ws_size;

  const int Nn = in_sizes[0] / 256;  // 50000
  const int Ee = in_sizes[1];        // 800000
  const int F = 256;
  const int NB = (Nn + 255) / 256;

  // workspace layout
  unsigned short* z   = (unsigned short*)d_ws;      // Nn*256 fp16
  unsigned short* xh  = z + (size_t)Nn * F;         // Nn*256 fp16 (x cvt; then h)
  unsigned short* w1t = xh + (size_t)Nn * F;        // 256*256 fp16
  unsigned short* w2t = w1t + 65536;                // 256*256 fp16
  int*   esrc   = (int*)(w2t + 65536);              // Ee
  int*   counts = esrc + Ee;                        // Nn
  int*   offs   = counts + Nn;                      // Nn
  int*   cursor = offs + Nn;                        // Nn (unused; layout kept)
  int*   bsum   = cursor + Nn;                      // 256
  int*   bofs   = bsum + 256;                       // 256 (unused; layout kept)
  float* el1p   = (float*)(bofs + 256);             // Nn*2
  float* er1p   = el1p + (size_t)Nn * 2;            // Nn*2
  float* el2p   = er1p + (size_t)Nn * 2;            // Nn
  float* er2p   = el2p + Nn;                        // Nn
  int*   erank  = (int*)z;                          // Ee, aliases z (dead until gemm1)

  dim3 blk(256);

  // ---- fused prep: transpose W1/W2 + zero counts..er2p + cvt x->fp16 ----
  const int zn4 = (9 * Nn + 512) / 4;       // ints / 4
  const int NZ = (zn4 + 255) / 256;
  const int n4cvt = Nn * 64;                // float4 count of x
  const int NC = (n4cvt + 255) / 256;
  prep<<<512 + NZ + NC, blk, 0, stream>>>(W1, W2, w1t, w2t, (const float4*)x,
                                          (uint2*)xh, n4cvt, (float4*)counts, zn4, NZ);

  // ---- CSR build: one returning-atomic pass + scan + placement ----
  const int EB = (Ee + 255) / 256;
  hist_rank<<<EB, blk, 0, stream>>>(dst, counts, erank, Ee);
  scan_block<<<NB, blk, 0, stream>>>(counts, offs, bsum, Nn);
  scan_add2<<<NB, blk, 0, stream>>>(offs, bsum, Nn, NB);
  scatter_pos<<<EB, blk, 0, stream>>>(src, dst, offs, erank, esrc, Ee);

  const int gemm_grid = 512;  // 2 blocks/CU

  // ---- layer 1 (heads=2, d=128) ----
  gemm_mfma<1><<<gemm_grid, blk, 0, stream>>>(xh, w1t, z, al1, ar1, el1p, er1p, Nn);
  node_aggregate<1, 1, 1><<<(Nn + 3) / 4, blk, 0, stream>>>(z, el1p, er1p, esrc, offs,
                                                            counts, b1, xh, 0, Nn);

  // ---- layer 2 (heads=1, d=256) ----
  gemm_mfma<0><<<gemm_grid, blk, 0, stream>>>(xh, w2t, z, al2, ar2, el2p, er2p, Nn);
  node_aggregate<0, 0, 0><<<(Nn + 3) / 4, blk, 0, stream>>>(z, el2p, er2p, esrc, offs,
                                                            counts, b2, out, 0, Nn);
}